// Round 12
// baseline (66.551 us; speedup 1.0000x reference)
//
#include <hip/hip_runtime.h>
#include <hip/hip_bf16.h>

// RoIAlign forward, aligned=True, sampling_ratio=2, pooled 7x7, scale 0.25.
// 3-kernel pipeline (kernel boundaries = cheap sync; grid.sync measured
// ~250us on gfx950 and is banned):
//  K1: transpose x[b=0] f32->bf16 channels-last + hidden bitonic ROI sort.
//  K2: even blocks transpose x[b=1] (HBM-bound) || odd blocks gather
//      batch-0 ROIs (L3-bound). Disjoint resources -> overlap.
//  K3: gather batch-1 ROIs.
// Gather block: (roi, channel-half), per-ROI bilinear tables in LDS, 8x16B
// corner loads per bin, x-corner partials via shfl_xor(16), 25KB LDS out
// stage, contiguous nontemporal write.

#define PH 7
#define PW 7
#define SCALE 0.25f
#define C_ 256
#define CH_ 128
#define H_ 200
#define W_ 200
#define HW_ (H_ * W_)
#define TILES 2500           // 64x64 transpose tiles per batch (625 hw x 4 ch)

typedef float f32x4 __attribute__((ext_vector_type(4)));

union SMemU {
    struct { float tile[64][65]; } a;
    struct {
        float s_out[CH_ * 49];
        int   ylo[14], yhi[14], xlo[14];
        float wy0[14], wy1[14], wx0[14], wx1[14];
        int   b;
    } r;
};

// ---- transpose one 64x64 tile of batch b (flat 512 threads) ----------------
__device__ __forceinline__ void do_tile(SMemU& sm, const float* __restrict__ x,
                                        __hip_bfloat16* __restrict__ xt,
                                        int b, int tt, int t) {
    int tx = t & 63, ty = t >> 6;
    int hw0 = (tt % 625) * 64;
    int c0  = (tt / 625) * 64;
    const float* xb = x + (size_t)b * C_ * HW_;
#pragma unroll
    for (int j = 0; j < 8; ++j) {
        int cl = ty + 8 * j;
        sm.a.tile[cl][tx] = __builtin_nontemporal_load(&xb[(size_t)(c0 + cl) * HW_ + hw0 + tx]);
    }
    __syncthreads();
    __hip_bfloat16* xtb = xt + (size_t)b * HW_ * C_;
#pragma unroll
    for (int j = 0; j < 8; ++j) {
        int rl = ty + 8 * j;
        xtb[(size_t)(hw0 + rl) * C_ + c0 + tx] = __float2bfloat16(sm.a.tile[tx][rl]);
    }
}

__device__ __forceinline__ void accum8(float* acc, uint4 v, float w) {
    const unsigned* a = (const unsigned*)&v;
#pragma unroll
    for (int i = 0; i < 4; ++i) {
        acc[2 * i]     = fmaf(w, __uint_as_float(a[i] << 16), acc[2 * i]);
        acc[2 * i + 1] = fmaf(w, __uint_as_float(a[i] & 0xffff0000u), acc[2 * i + 1]);
    }
}

// ---- gather one (roi, channel-half) task (flat 512 threads) ----------------
__device__ __forceinline__ void do_roi(SMemU& sm, const __hip_bfloat16* __restrict__ xt,
                                       const float* __restrict__ rois,
                                       float* __restrict__ out,
                                       int k, int chalf, int t) {
    const float* r = rois + (size_t)k * 5;
    if (t == 0) sm.r.b = (int)r[0];
    if (t < 28) {
        bool isy = t < 14;
        int i = isy ? t : t - 14;
        float start = (isy ? r[2] : r[1]) * SCALE - 0.5f;
        float end   = (isy ? r[4] : r[3]) * SCALE - 0.5f;
        float bin = (end - start) * (1.0f / 7.0f);
        int limit = isy ? H_ : W_;
        float pp   = (float)(i >> 1);
        float soff = (i & 1) ? 0.75f : 0.25f;
        float coord = fmaf(pp + soff, bin, start);
        float valid = (coord >= -1.0f && coord <= (float)limit) ? 1.0f : 0.0f;
        float cc = fmaxf(coord, 0.0f);
        int low0 = (int)floorf(cc);
        bool cap = low0 >= limit - 1;
        int lo = cap ? limit - 1 : low0;
        int hi = cap ? limit - 1 : low0 + 1;
        cc = cap ? (float)lo : cc;
        float l = cc - (float)lo;
        float w1 = l * valid, w0 = (1.0f - l) * valid;
        if (isy) {
            sm.r.ylo[i] = lo; sm.r.yhi[i] = hi;
            sm.r.wy0[i] = w0 * 0.25f; sm.r.wy1[i] = w1 * 0.25f;   // fold 1/4 avg
        } else {
            sm.r.xlo[i] = lo;
            sm.r.wx0[i] = w0; sm.r.wx1[i] = w1;
        }
    }
    __syncthreads();

    int cgi   = t & 15;
    int xc    = (t >> 4) & 1;
    int pslot = t >> 5;

    const __hip_bfloat16* xb = xt + (size_t)sm.r.b * HW_ * C_ + chalf * CH_ + cgi * 8;

    for (int p = pslot; p < 49; p += 16) {
        int ph = p / 7;
        int pw = p - ph * 7;
        int ys0 = 2 * ph, xs0 = 2 * pw;
        int yl0 = sm.r.ylo[ys0],     yh0 = sm.r.yhi[ys0];
        int yl1 = sm.r.ylo[ys0 + 1], yh1 = sm.r.yhi[ys0 + 1];
        int xi0 = sm.r.xlo[xs0] + xc;
        int xi1 = sm.r.xlo[xs0 + 1] + xc;
        float wxa = xc ? sm.r.wx1[xs0]     : sm.r.wx0[xs0];
        float wxb = xc ? sm.r.wx1[xs0 + 1] : sm.r.wx0[xs0 + 1];
        float wA = sm.r.wy0[ys0] * wxa,     wB = sm.r.wy1[ys0] * wxa;
        float wC = sm.r.wy0[ys0] * wxb,     wD = sm.r.wy1[ys0] * wxb;
        float wE = sm.r.wy0[ys0 + 1] * wxa, wF = sm.r.wy1[ys0 + 1] * wxa;
        float wG = sm.r.wy0[ys0 + 1] * wxb, wH = sm.r.wy1[ys0 + 1] * wxb;

        uint4 v0 = *(const uint4*)(xb + ((size_t)(yl0 * W_ + xi0) << 8));
        uint4 v1 = *(const uint4*)(xb + ((size_t)(yh0 * W_ + xi0) << 8));
        uint4 v2 = *(const uint4*)(xb + ((size_t)(yl0 * W_ + xi1) << 8));
        uint4 v3 = *(const uint4*)(xb + ((size_t)(yh0 * W_ + xi1) << 8));
        uint4 v4 = *(const uint4*)(xb + ((size_t)(yl1 * W_ + xi0) << 8));
        uint4 v5 = *(const uint4*)(xb + ((size_t)(yh1 * W_ + xi0) << 8));
        uint4 v6 = *(const uint4*)(xb + ((size_t)(yl1 * W_ + xi1) << 8));
        uint4 v7 = *(const uint4*)(xb + ((size_t)(yh1 * W_ + xi1) << 8));

        float acc[8];
#pragma unroll
        for (int j = 0; j < 8; ++j) acc[j] = 0.0f;
        accum8(acc, v0, wA);
        accum8(acc, v1, wB);
        accum8(acc, v2, wC);
        accum8(acc, v3, wD);
        accum8(acc, v4, wE);
        accum8(acc, v5, wF);
        accum8(acc, v6, wG);
        accum8(acc, v7, wH);

#pragma unroll
        for (int j = 0; j < 8; ++j) {
            float v = acc[j] + __shfl_xor(acc[j], 16, 64);
            if (xc == 0) sm.r.s_out[(cgi * 8 + j) * 49 + p] = v;
        }
    }
    __syncthreads();

    const f32x4* sv = (const f32x4*)sm.r.s_out;
    f32x4* ov = (f32x4*)(out + ((size_t)k * C_ + chalf * CH_) * 49);
    for (int i = t; i < (CH_ * 49) / 4; i += 512)
        __builtin_nontemporal_store(sv[i], &ov[i]);
}

// ---- K1: transpose batch 0 + hidden sort -----------------------------------
__global__ void __launch_bounds__(512)
transpose_sort_kernel(const float* __restrict__ x, __hip_bfloat16* __restrict__ xt,
                      const float* __restrict__ rois, int K, int mode, int B,
                      int* __restrict__ perm) {
    __shared__ SMemU sm;
    __shared__ int s[1024];
    int bx = blockIdx.x;
    int t = threadIdx.x;

    if (bx == gridDim.x - 1) {
        if (blockIdx.z != 0) return;
        if (mode == 1) {
            for (int i = t; i < 1024; i += 512) {
                int key = 0x7FFFFFFF;
                if (i < K) {
                    const float* r = rois + (size_t)i * 5;
                    int b = (int)r[0];
                    float yc = (r[2] + r[4]) * (0.5f * SCALE);
                    int yq = min(max((int)yc, 0), 511);
                    key = ((b * 512 + yq) << 12) | i;
                }
                s[i] = key;
            }
            __syncthreads();
            for (int k2 = 2; k2 <= 1024; k2 <<= 1) {
                for (int j = k2 >> 1; j > 0; j >>= 1) {
                    int i = ((t & ~(j - 1)) << 1) | (t & (j - 1));
                    int l = i | j;
                    int a = s[i], b = s[l];
                    bool up = ((i & k2) == 0);
                    if ((a > b) == up) { s[i] = b; s[l] = a; }
                    __syncthreads();
                }
            }
            for (int i = t; i < K; i += 512) perm[i] = s[i] & 0xFFF;
        } else {
            for (int i = t; i < K; i += 512) perm[i] = i;
        }
        return;
    }
    // batch index from z (K1 uses z=0 only; mode-0 path uses z=0..B-1)
    do_tile(sm, x, xt, blockIdx.z, bx, t);
}

// ---- K2: transpose batch 1 (even bids) || gather batch-0 ROIs (odd bids) ---
__global__ void __launch_bounds__(512)
mixed_kernel(const float* __restrict__ x, __hip_bfloat16* __restrict__ xt,
             const float* __restrict__ rois, const int* __restrict__ perm,
             float* __restrict__ out, int K) {
    __shared__ SMemU sm;
    int bid = blockIdx.x;
    int t = threadIdx.x;
    if ((bid & 1) == 0) {
        int tt = bid >> 1;
        if (tt < TILES) do_tile(sm, x, xt, 1, tt, t);
        return;
    }
    int task = bid >> 1;
    if (task >= 2 * K) return;
    int rank  = task >> 1;
    int chalf = task & 1;
    int k = perm[rank];
    if (rois[(size_t)k * 5] >= 0.5f) return;   // batch-1: handled by K3
    do_roi(sm, xt, rois, out, k, chalf, t);
}

// ---- K3: gather batch-1 ROIs (XCD-chunked over sorted order) ---------------
__global__ void __launch_bounds__(512)
roi_main(const __hip_bfloat16* __restrict__ xt, const float* __restrict__ rois,
         const int* __restrict__ perm, float* __restrict__ out, int K,
         int mode, int want) {
    __shared__ SMemU sm;
    int k, chalf;
    if (mode == 1) {
        int xcd  = blockIdx.x & 7;
        int pos  = blockIdx.x >> 3;
        chalf    = xcd >> 2;
        int rank = (xcd & 3) * (K >> 2) + pos;
        k = perm[rank];
    } else {
        int nwg = gridDim.x;
        int q = nwg >> 3, rr = nwg & 7;
        int xcd = blockIdx.x & 7, pos = blockIdx.x >> 3;
        int logical = (xcd < rr ? xcd * (q + 1) : rr * (q + 1) + (xcd - rr) * q) + pos;
        k = perm[logical >> 1];
        chalf = logical & 1;
    }
    if (want >= 0 && (int)rois[(size_t)k * 5] != want) return;
    do_roi(sm, xt, rois, out, k, chalf, threadIdx.x);
}

// ---- fallback (round-1 kernel) ---------------------------------------------
__device__ __forceinline__ void axis_sample(float coord, int limit,
                                            int& lo, int& hi,
                                            float& w0, float& w1) {
    float fl = (float)limit;
    float valid = (coord >= -1.0f && coord <= fl) ? 1.0f : 0.0f;
    float c = fmaxf(coord, 0.0f);
    int low0 = (int)floorf(c);
    bool cap = low0 >= limit - 1;
    lo = cap ? limit - 1 : low0;
    hi = cap ? limit - 1 : low0 + 1;
    c = cap ? (float)lo : c;
    float l = c - (float)lo;
    w1 = l * valid;
    w0 = (1.0f - l) * valid;
}

__global__ void __launch_bounds__(256)
roi_align_fallback(const float* __restrict__ x, const float* __restrict__ rois,
                   float* __restrict__ out, int total) {
    int idx = blockIdx.x * blockDim.x + threadIdx.x;
    if (idx >= total) return;
    int pw = idx % PW;
    int ph = (idx / PW) % PH;
    int c  = (idx / (PW * PH)) % C_;
    int k  = idx / (PW * PH * C_);
    const float* r = rois + (size_t)k * 5;
    int b = (int)r[0];
    float start_w = r[1] * SCALE - 0.5f;
    float start_h = r[2] * SCALE - 0.5f;
    float bin_w = (r[3] * SCALE - 0.5f - start_w) / (float)PW;
    float bin_h = (r[4] * SCALE - 0.5f - start_h) / (float)PH;
    const float* xp = x + ((size_t)b * C_ + c) * (size_t)HW_;
    float acc = 0.0f;
#pragma unroll
    for (int sy = 0; sy < 2; ++sy) {
        float yc = start_h + ((float)ph + (sy + 0.5f) * 0.5f) * bin_h;
        int yl, yh; float wy0, wy1;
        axis_sample(yc, H_, yl, yh, wy0, wy1);
        const float* row0 = xp + (size_t)yl * W_;
        const float* row1 = xp + (size_t)yh * W_;
#pragma unroll
        for (int sx = 0; sx < 2; ++sx) {
            float xc2 = start_w + ((float)pw + (sx + 0.5f) * 0.5f) * bin_w;
            int xl, xh; float wx0, wx1;
            axis_sample(xc2, W_, xl, xh, wx0, wx1);
            acc += wy0 * (wx0 * row0[xl] + wx1 * row0[xh])
                 + wy1 * (wx0 * row1[xl] + wx1 * row1[xh]);
        }
    }
    out[idx] = acc * 0.25f;
}

extern "C" void kernel_launch(void* const* d_in, const int* in_sizes, int n_in,
                              void* d_out, int out_size, void* d_ws, size_t ws_size,
                              hipStream_t stream) {
    const float* x    = (const float*)d_in[0];
    const float* rois = (const float*)d_in[1];
    float* out = (float*)d_out;
    int K = in_sizes[1] / 5;
    int B = in_sizes[0] / (C_ * HW_);

    size_t xtbytes = (size_t)B * HW_ * C_ * sizeof(__hip_bfloat16);
    size_t need = xtbytes + 4096 * sizeof(int);
    bool ok = (B >= 1 && B <= 8 && ws_size >= need && K >= 8 && K <= 1024);
    if (ok && B == 2 && (K % 4) == 0) {
        // 3-kernel pipeline
        __hip_bfloat16* xt = (__hip_bfloat16*)d_ws;
        int* perm = (int*)((char*)d_ws + xtbytes);
        transpose_sort_kernel<<<dim3(TILES + 1, 1, 1), 512, 0, stream>>>(
            x, xt, rois, K, 1, B, perm);
        int g2 = 2 * ((TILES > 2 * K) ? TILES : 2 * K);
        mixed_kernel<<<g2, 512, 0, stream>>>(x, xt, rois, perm, out, K);
        roi_main<<<K * 2, 512, 0, stream>>>(xt, rois, perm, out, K, 1, 1);
    } else if (ok) {
        // two-kernel path (no batch pipelining)
        __hip_bfloat16* xt = (__hip_bfloat16*)d_ws;
        int* perm = (int*)((char*)d_ws + xtbytes);
        transpose_sort_kernel<<<dim3(TILES + 1, 1, B), 512, 0, stream>>>(
            x, xt, rois, K, 0, B, perm);
        roi_main<<<K * 2, 512, 0, stream>>>(xt, rois, perm, out, K, 0, -1);
    } else {
        int total = K * C_ * PH * PW;
        roi_align_fallback<<<(total + 255) / 256, 256, 0, stream>>>(x, rois, out, total);
    }
}

// Round 13
// 51.408 us; speedup vs baseline: 1.2946x; 1.2946x over previous
//
#include <hip/hip_runtime.h>
#include <hip/hip_bf16.h>

// RoIAlign forward, aligned=True, sampling_ratio=2, pooled 7x7, scale 0.25.
// FINAL (round-7 configuration, best measured 51.3us):
// (1) transpose x [B,C,H,W] f32 -> xt [B,H*W,C] bf16; one extra block in the
//     same kernel bitonic-sorts ROIs by (batch, y-center) -> perm.
// (2) roi_main: 2 blocks per ROI (channel halves), chalf = XCD>=4, sorted-ROI
//     chunks per XCD&3. Lanes: cg=t&15 (8ch each), xc=bit4 (x-corner) so the
//     (yl,xl)+(yl,xh) pair is one contiguous 512B span per 32 lanes;
//     x-corner partials combined via shfl_xor(16). 25KB LDS out stage, one
//     contiguous nontemporal write.
// Falsified by measurement (do NOT retry): grid.sync overlap (~250us, r10),
// even/odd kernel interleave overlap (+15us, r12), 4-way channel slicing
// (r8), upfront-8-load MLP (r11).

#define PH 7
#define PW 7
#define SCALE 0.25f
#define C_ 256
#define CH_ 128
#define H_ 200
#define W_ 200
#define HW_ (H_ * W_)

typedef float f32x4 __attribute__((ext_vector_type(4)));

// -------- transpose + hidden ROI sort ---------------------------------------
__global__ void __launch_bounds__(512)
transpose_sort_kernel(const float* __restrict__ x, __hip_bfloat16* __restrict__ xt,
                      const float* __restrict__ rois, int K, int mode,
                      int* __restrict__ perm) {
    __shared__ float tile[64][65];
    __shared__ int s[1024];
    int bx = blockIdx.x;
    int tx = threadIdx.x;   // 0..63
    int ty = threadIdx.y;   // 0..7
    int t = ty * 64 + tx;   // 0..511

    if (bx == gridDim.x - 1) {
        if (blockIdx.y != 0 || blockIdx.z != 0) return;
        if (mode == 1) {
            for (int i = t; i < 1024; i += 512) {
                int key = 0x7FFFFFFF;
                if (i < K) {
                    const float* r = rois + (size_t)i * 5;
                    int b = (int)r[0];
                    float yc = (r[2] + r[4]) * (0.5f * SCALE);
                    int yq = min(max((int)yc, 0), 511);
                    key = ((b * 512 + yq) << 12) | i;
                }
                s[i] = key;
            }
            __syncthreads();
            for (int k2 = 2; k2 <= 1024; k2 <<= 1) {
                for (int j = k2 >> 1; j > 0; j >>= 1) {
                    int i = ((t & ~(j - 1)) << 1) | (t & (j - 1));
                    int l = i | j;
                    int a = s[i], b = s[l];
                    bool up = ((i & k2) == 0);
                    if ((a > b) == up) { s[i] = b; s[l] = a; }
                    __syncthreads();
                }
            }
            for (int i = t; i < K; i += 512) perm[i] = s[i] & 0xFFF;
        } else {
            for (int i = t; i < K; i += 512) perm[i] = i;
        }
        return;
    }

    int hw0 = bx * 64;
    int c0  = blockIdx.y * 64;
    int b   = blockIdx.z;
    const float* xb = x + (size_t)b * C_ * HW_;
#pragma unroll
    for (int j = 0; j < 8; ++j) {
        int cl = ty + 8 * j;
        tile[cl][tx] = __builtin_nontemporal_load(&xb[(size_t)(c0 + cl) * HW_ + hw0 + tx]);
    }
    __syncthreads();
    __hip_bfloat16* xtb = xt + (size_t)b * HW_ * C_;
#pragma unroll
    for (int j = 0; j < 8; ++j) {
        int rl = ty + 8 * j;
        xtb[(size_t)(hw0 + rl) * C_ + c0 + tx] = __float2bfloat16(tile[tx][rl]);
    }
}

// -------- main: 2 blocks (512 thr) per ROI ----------------------------------
__global__ void __launch_bounds__(512)
roi_main(const __hip_bfloat16* __restrict__ xt, const float* __restrict__ rois,
         const int* __restrict__ perm, float* __restrict__ out, int K, int mode) {
    __shared__ float s_out[CH_ * 49];         // 25088 B
    __shared__ int   s_ylo[14], s_yhi[14], s_xlo[14];
    __shared__ float s_wy0[14], s_wy1[14], s_wx0[14], s_wx1[14];
    __shared__ int   s_b;

    int k, chalf;
    if (mode == 1) {
        int xcd  = blockIdx.x & 7;
        int pos  = blockIdx.x >> 3;
        chalf    = xcd >> 2;
        int rank = (xcd & 3) * (K >> 2) + pos;
        k = perm[rank];
    } else {
        int nwg = gridDim.x;
        int q = nwg >> 3, rr = nwg & 7;
        int xcd = blockIdx.x & 7, pos = blockIdx.x >> 3;
        int logical = (xcd < rr ? xcd * (q + 1) : rr * (q + 1) + (xcd - rr) * q) + pos;
        k = perm[logical >> 1];
        chalf = logical & 1;
    }

    int t = threadIdx.x;
    const float* r = rois + (size_t)k * 5;
    if (t == 0) s_b = (int)r[0];
    if (t < 28) {
        bool isy = t < 14;
        int i = isy ? t : t - 14;
        float start = (isy ? r[2] : r[1]) * SCALE - 0.5f;
        float end   = (isy ? r[4] : r[3]) * SCALE - 0.5f;
        float bin = (end - start) * (1.0f / 7.0f);
        int limit = isy ? H_ : W_;
        float pp   = (float)(i >> 1);
        float soff = (i & 1) ? 0.75f : 0.25f;
        float coord = fmaf(pp + soff, bin, start);
        float valid = (coord >= -1.0f && coord <= (float)limit) ? 1.0f : 0.0f;
        float cc = fmaxf(coord, 0.0f);
        int low0 = (int)floorf(cc);
        bool cap = low0 >= limit - 1;
        int lo = cap ? limit - 1 : low0;
        int hi = cap ? limit - 1 : low0 + 1;
        cc = cap ? (float)lo : cc;
        float l = cc - (float)lo;
        float w1 = l * valid, w0 = (1.0f - l) * valid;
        if (isy) {
            s_ylo[i] = lo; s_yhi[i] = hi;
            s_wy0[i] = w0 * 0.25f; s_wy1[i] = w1 * 0.25f;   // fold 1/4 average
        } else {
            s_xlo[i] = lo;
            s_wx0[i] = w0; s_wx1[i] = w1;
        }
    }
    __syncthreads();

    int cg    = t & 15;        // channels 8*cg..8*cg+7 within the half
    int xc    = (t >> 4) & 1;  // which x-corner this lane accumulates
    int pslot = t >> 5;        // 0..15 -> p = pslot, pslot+16, ...

    const __hip_bfloat16* xb = xt + (size_t)s_b * HW_ * C_ + chalf * CH_ + cg * 8;

    for (int p = pslot; p < 49; p += 16) {
        int ph = p / 7;
        int pw = p - ph * 7;
        float acc[8];
#pragma unroll
        for (int j = 0; j < 8; ++j) acc[j] = 0.0f;

#pragma unroll
        for (int sy = 0; sy < 2; ++sy) {
            int ys = 2 * ph + sy;
            int yl = s_ylo[ys], yh = s_yhi[ys];
            float wy0 = s_wy0[ys], wy1 = s_wy1[ys];
#pragma unroll
            for (int sx = 0; sx < 2; ++sx) {
                int xs = 2 * pw + sx;
                int xi = s_xlo[xs] + xc;   // xc=1: xl+1 (=xh except cap, weight 0)
                float wxm = xc ? s_wx1[xs] : s_wx0[xs];
                float wl = wy0 * wxm, wh = wy1 * wxm;
                uint4 vlo = *(const uint4*)(xb + ((size_t)(yl * W_ + xi) << 8));
                uint4 vhi = *(const uint4*)(xb + ((size_t)(yh * W_ + xi) << 8));
                const unsigned* alo = (const unsigned*)&vlo;
                const unsigned* ahi = (const unsigned*)&vhi;
#pragma unroll
                for (int w = 0; w < 4; ++w) {
                    float flo0 = __uint_as_float(alo[w] << 16);
                    float flo1 = __uint_as_float(alo[w] & 0xffff0000u);
                    float fhi0 = __uint_as_float(ahi[w] << 16);
                    float fhi1 = __uint_as_float(ahi[w] & 0xffff0000u);
                    acc[2 * w]     = fmaf(wl, flo0, acc[2 * w]);
                    acc[2 * w]     = fmaf(wh, fhi0, acc[2 * w]);
                    acc[2 * w + 1] = fmaf(wl, flo1, acc[2 * w + 1]);
                    acc[2 * w + 1] = fmaf(wh, fhi1, acc[2 * w + 1]);
                }
            }
        }
#pragma unroll
        for (int j = 0; j < 8; ++j) {
            float v = acc[j] + __shfl_xor(acc[j], 16, 64);
            if (xc == 0) s_out[(cg * 8 + j) * 49 + p] = v;
        }
    }
    __syncthreads();

    const f32x4* sv = (const f32x4*)s_out;
    f32x4* ov = (f32x4*)(out + ((size_t)k * C_ + chalf * CH_) * 49);
    for (int i = t; i < (CH_ * 49) / 4; i += 512)
        __builtin_nontemporal_store(sv[i], &ov[i]);
}

// -------- fallback (round-1 kernel) if ws too small -------------------------
__device__ __forceinline__ void axis_sample(float coord, int limit,
                                            int& lo, int& hi,
                                            float& w0, float& w1) {
    float fl = (float)limit;
    float valid = (coord >= -1.0f && coord <= fl) ? 1.0f : 0.0f;
    float c = fmaxf(coord, 0.0f);
    int low0 = (int)floorf(c);
    bool cap = low0 >= limit - 1;
    lo = cap ? limit - 1 : low0;
    hi = cap ? limit - 1 : low0 + 1;
    c = cap ? (float)lo : c;
    float l = c - (float)lo;
    w1 = l * valid;
    w0 = (1.0f - l) * valid;
}

__global__ void __launch_bounds__(256)
roi_align_fallback(const float* __restrict__ x, const float* __restrict__ rois,
                   float* __restrict__ out, int total) {
    int idx = blockIdx.x * blockDim.x + threadIdx.x;
    if (idx >= total) return;
    int pw = idx % PW;
    int ph = (idx / PW) % PH;
    int c  = (idx / (PW * PH)) % C_;
    int k  = idx / (PW * PH * C_);
    const float* r = rois + (size_t)k * 5;
    int b = (int)r[0];
    float start_w = r[1] * SCALE - 0.5f;
    float start_h = r[2] * SCALE - 0.5f;
    float bin_w = (r[3] * SCALE - 0.5f - start_w) / (float)PW;
    float bin_h = (r[4] * SCALE - 0.5f - start_h) / (float)PH;
    const float* xp = x + ((size_t)b * C_ + c) * (size_t)HW_;
    float acc = 0.0f;
#pragma unroll
    for (int sy = 0; sy < 2; ++sy) {
        float yc = start_h + ((float)ph + (sy + 0.5f) * 0.5f) * bin_h;
        int yl, yh; float wy0, wy1;
        axis_sample(yc, H_, yl, yh, wy0, wy1);
        const float* row0 = xp + (size_t)yl * W_;
        const float* row1 = xp + (size_t)yh * W_;
#pragma unroll
        for (int sx = 0; sx < 2; ++sx) {
            float xc2 = start_w + ((float)pw + (sx + 0.5f) * 0.5f) * bin_w;
            int xl, xh; float wx0, wx1;
            axis_sample(xc2, W_, xl, xh, wx0, wx1);
            acc += wy0 * (wx0 * row0[xl] + wx1 * row0[xh])
                 + wy1 * (wx0 * row1[xl] + wx1 * row1[xh]);
        }
    }
    out[idx] = acc * 0.25f;
}

extern "C" void kernel_launch(void* const* d_in, const int* in_sizes, int n_in,
                              void* d_out, int out_size, void* d_ws, size_t ws_size,
                              hipStream_t stream) {
    const float* x    = (const float*)d_in[0];
    const float* rois = (const float*)d_in[1];
    float* out = (float*)d_out;
    int K = in_sizes[1] / 5;
    int B = in_sizes[0] / (C_ * HW_);

    size_t xtbytes = (size_t)B * HW_ * C_ * sizeof(__hip_bfloat16);
    size_t need = xtbytes + 4096 * sizeof(int);
    if (B >= 1 && B <= 8 && ws_size >= need && K <= 4096 && K >= 8) {
        __hip_bfloat16* xt = (__hip_bfloat16*)d_ws;
        int* perm = (int*)((char*)d_ws + xtbytes);
        int mode = (K % 4 == 0 && K <= 1024 && B <= 2) ? 1 : 0;
        dim3 tgrid(HW_ / 64 + 1, C_ / 64, B);   // +1: sort block
        dim3 tblock(64, 8);
        transpose_sort_kernel<<<tgrid, tblock, 0, stream>>>(x, xt, rois, K, mode, perm);
        roi_main<<<K * 2, 512, 0, stream>>>(xt, rois, perm, out, K, mode);
    } else {
        int total = K * C_ * PH * PW;
        roi_align_fallback<<<(total + 255) / 256, 256, 0, stream>>>(x, rois, out, total);
    }
}